// Round 11
// baseline (192.010 us; speedup 1.0000x reference)
//
#include <hip/hip_runtime.h>
#include <math.h>

#define BB 8
#define CCH 32
#define HH 128
#define WW 128
#define OUTC 32
#define NPIX (BB*HH*WW)          // 131072
#define HWP 131                   // padded-coord clamp limit

// workspace layout (float offsets) — ~18.9 MB
#define WS_XT    0                                   // fp32 x_t [b][i][j][c], 16 MB
#define WS_CONV4 (BB*HH*WW*CCH)                      // pre-BN conv, 4 f/px, 2 MB
#define WS_STATS (WS_CONV4 + BB*HH*WW*4)             // 8 f
#define WS_BNAB  (WS_STATS + 8)                      // 8 f
#define WS_WKB   (WS_BNAB + 8)                       // 16384 ushort bf16 W[o][k]
#define WS_WCV   (WS_WKB + 8192)                     // 896 f: wcv[7][32][2], whz[7][32][2]

// k_main LDS tile: offset(r,cc,q) = ((r*72+cc)*5 + q)*8 ushorts; 80B stride -> conflict-free
#define TILE_USH (9*72*5*8)                          // 51840 B

typedef __attribute__((ext_vector_type(8))) short short8;
typedef __attribute__((ext_vector_type(4))) float f32x4;

__device__ __forceinline__ unsigned short f2bf(float f) {
    unsigned u = __float_as_uint(f);
    unsigned r = (u + 0x7FFFu + ((u >> 16) & 1u)) >> 16;   // RTNE
    return (unsigned short)r;
}
__device__ __forceinline__ unsigned pk2(float a, float b) {
    return (unsigned)f2bf(a) | ((unsigned)f2bf(b) << 16);
}
__device__ __forceinline__ float bflo(unsigned w) { return __uint_as_float(w << 16); }
__device__ __forceinline__ float bfhi(unsigned w) { return __uint_as_float(w & 0xFFFF0000u); }

// ---------------- K1: transpose x -> x_t fp32; zero stats; build conv wtabs -
__global__ __launch_bounds__(256) void k_transpose(const float* __restrict__ x,
        const float* __restrict__ w_vrt, const float* __restrict__ w_hrz,
        float* __restrict__ ws) {
    __shared__ float tile[32][33];
    int blk = blockIdx.x;            // b*H*(W/32)
    int j0 = (blk & 3) << 5;
    int bi = blk >> 2;               // b*H + i
    int b = bi >> 7, i = bi & 127;
    int tx = threadIdx.x & 31;
    int ty = threadIdx.x >> 5;       // 0..7
    #pragma unroll
    for (int c = ty; c < 32; c += 8)
        tile[c][tx] = x[(((size_t)b*CCH + c)*HH + i)*WW + j0 + tx];
    __syncthreads();
    float* xt = ws + WS_XT;
    #pragma unroll
    for (int jj = ty; jj < 32; jj += 8)
        xt[(((size_t)bi)*WW + j0 + jj)*CCH + tx] = tile[tx][jj];
    if (blk == 0) {
        if (threadIdx.x < 8) ws[WS_STATS + threadIdx.x] = 0.f;
        // wcv[k][c][oc] = w_vrt[oc*224 + c*7 + k]; whz likewise (fp32)
        for (int e = threadIdx.x; e < 448; e += 256) {
            int k = e >> 6, c = (e >> 1) & 31, oc = e & 1;
            ws[WS_WCV + e]       = w_vrt[oc*224 + c*7 + k];
            ws[WS_WCV + 448 + e] = w_hrz[oc*224 + c*7 + k];
        }
    }
}

// ---------------- K2: 7-tap convs, fp32 global coalesced --------------------
// block = 64 px of one row; thread = (px = t>>2, q = t&3 -> channels q*8..+7).
// Wave reads 16 px x 32 ch = 2KB contiguous per tap. Gates stay fp32 end-to-end
// (bf16 conv input flips floor() in the discontinuous 2-corner interp - R5/6/10).
__global__ __launch_bounds__(256) void k_conv(float* __restrict__ ws,
        const float* __restrict__ b_vrt, const float* __restrict__ b_hrz) {
    __shared__ float red2[4][8];
    const float* xt  = ws + WS_XT;
    const float* wcv = ws + WS_WCV;
    const float* whz = ws + WS_WCV + 448;
    int t = threadIdx.x;
    int q = t & 3, px = t >> 2;
    int idx0 = blockIdx.x * 64;
    int b = idx0 >> 14, ij0 = idx0 & 16383, i = ij0 >> 7, j0 = ij0 & 127;
    int j = j0 + px;
    const float* xb = xt + (size_t)b * (HH*WW*CCH);
    float v0 = 0.f, v1 = 0.f, h0 = 0.f, h1 = 0.f;
    #pragma unroll
    for (int k = 0; k < 7; k++) {
        int gr = i + k - 3;
        if (gr >= 0 && gr < HH) {
            const float4* p = (const float4*)(xb + ((size_t)gr*WW + j)*CCH + q*8);
            float4 a = p[0], c = p[1];
            const float4* wp = (const float4*)(wcv + (size_t)(k*32 + q*8)*2);
            float4 w0 = wp[0], w1 = wp[1], w2 = wp[2], w3 = wp[3];
            v0 += w0.x*a.x + w0.z*a.y + w1.x*a.z + w1.z*a.w
                + w2.x*c.x + w2.z*c.y + w3.x*c.z + w3.z*c.w;
            v1 += w0.y*a.x + w0.w*a.y + w1.y*a.z + w1.w*a.w
                + w2.y*c.x + w2.w*c.y + w3.y*c.z + w3.w*c.w;
        }
        int gc = j + k - 3;
        if (gc >= 0 && gc < WW) {
            const float4* p = (const float4*)(xb + ((size_t)i*WW + gc)*CCH + q*8);
            float4 a = p[0], c = p[1];
            const float4* wp = (const float4*)(whz + (size_t)(k*32 + q*8)*2);
            float4 w0 = wp[0], w1 = wp[1], w2 = wp[2], w3 = wp[3];
            h0 += w0.x*a.x + w0.z*a.y + w1.x*a.z + w1.z*a.w
                + w2.x*c.x + w2.z*c.y + w3.x*c.z + w3.z*c.w;
            h1 += w0.y*a.x + w0.w*a.y + w1.y*a.z + w1.w*a.w
                + w2.y*c.x + w2.w*c.y + w3.y*c.z + w3.w*c.w;
        }
    }
    // group-of-4 lane reduction: lanes 4p..4p+3 share pixel p
    v0 += __shfl_xor(v0, 1); v0 += __shfl_xor(v0, 2);
    v1 += __shfl_xor(v1, 1); v1 += __shfl_xor(v1, 2);
    h0 += __shfl_xor(h0, 1); h0 += __shfl_xor(h0, 2);
    h1 += __shfl_xor(h1, 1); h1 += __shfl_xor(h1, 2);
    float fv0 = v0 + b_vrt[0], fv1 = v1 + b_vrt[1];
    float fh0 = h0 + b_hrz[0], fh1 = h1 + b_hrz[1];
    if (q == 0) {
        float4* conv4 = (float4*)(ws + WS_CONV4);
        conv4[idx0 + px] = make_float4(fv0, fv1, fh0, fh1);
    }
    // stats: count each pixel once (q==0 lanes), wave-reduce, cross-wave LDS
    float z = (q == 0) ? 1.f : 0.f;
    float stv[8] = {fv0*z, fv1*z, fh0*z, fh1*z,
                    fv0*fv0*z, fv1*fv1*z, fh0*fh0*z, fh1*fh1*z};
    int lane = t & 63, wave = t >> 6;
    #pragma unroll
    for (int u = 0; u < 8; u++) {
        float s = stv[u];
        for (int off = 32; off; off >>= 1) s += __shfl_down(s, off);
        if (lane == 0) red2[wave][u] = s;
    }
    __syncthreads();
    if (t < 8)
        atomicAdd(ws + WS_STATS + t,
                  red2[0][t] + red2[1][t] + red2[2][t] + red2[3][t]);
}

// ---------------- K3: BN affine consts + bf16 weight table W[o][k] ----------
__global__ void k_prep(const float* __restrict__ w_pk,
        const float* __restrict__ g_vrt, const float* __restrict__ be_vrt,
        const float* __restrict__ g_hrz, const float* __restrict__ be_hrz,
        float* __restrict__ ws) {
    unsigned short* wkb = (unsigned short*)(ws + WS_WKB);
    int e0 = blockIdx.x * 2048 + threadIdx.x;
    for (int e = e0; e < (blockIdx.x + 1) * 2048; e += 256) {
        int o = e >> 9, n = (e >> 5) & 15, c = e & 31;
        wkb[o*512 + n*32 + c] = f2bf(w_pk[((o*32 + c) << 4) + n]);
    }
    if (blockIdx.x == 0 && threadIdx.x < 4) {
        int t = threadIdx.x;
        const float cnt = (float)NPIX;
        float sum = ws[WS_STATS + t], sq = ws[WS_STATS + 4 + t];
        float mean = sum / cnt;
        float var  = sq / cnt - mean * mean;
        float gamma = (t < 2) ? g_vrt[t] : g_hrz[t - 2];
        float beta  = (t < 2) ? be_vrt[t] : be_hrz[t - 2];
        float a = gamma * rsqrtf(var + 1e-5f);
        ws[WS_BNAB + t]     = a;
        ws[WS_BNAB + 4 + t] = beta - mean * a;
    }
}

// ---------------- K4: LDS-tiled gather + interp + MFMA (R10 version) --------
__global__ __launch_bounds__(256) void k_main(const float* __restrict__ ws,
        const float* __restrict__ b_pk, float* __restrict__ out) {
    __shared__ unsigned short tile[TILE_USH];     // 51840 B
    const float* xt   = ws + WS_XT;
    const float* bnab = ws + WS_BNAB;
    const unsigned short* wkb = (const unsigned short*)(ws + WS_WKB);
    const float prfx[16] = {-2,-2,-2,-2, -2,-1, 0, 1,  2, 2, 2, 2, -1, 0, 1, 2};
    const float prfy[16] = {-2,-1, 0, 1,  2, 2, 2, 2, -1, 0, 1, 2, -2,-2,-2,-2};

    int t = threadIdx.x;
    int idx0 = blockIdx.x * 64;
    int b = idx0 >> 14, ij0 = idx0 & 16383, i = ij0 >> 7, j0 = ij0 & 127;

    // ---- coalesced tile load (fp32 -> bf16, edge clamp)
    for (int s = t; s < 9*72*4; s += 256) {
        int q = s & 3, cc = (s >> 2) % 72, r = (s >> 2) / 72;
        int gr = min(max(i - 4 + r, 0), HH - 1);
        int gc = min(max(j0 - 4 + cc, 0), WW - 1);
        const float4* src = (const float4*)(xt + (((size_t)(b*HH + gr))*WW + gc)*CCH + q*8);
        float4 f0 = src[0], f1 = src[1];
        uint4 v;
        v.x = pk2(f0.x, f0.y); v.y = pk2(f0.z, f0.w);
        v.z = pk2(f1.x, f1.y); v.w = pk2(f1.z, f1.w);
        *(uint4*)(tile + ((r*72 + cc)*5 + q)*8) = v;
    }
    __syncthreads();

    int w = t >> 6, pl = t & 15, quad = (t >> 4) & 3;
    int pix = idx0 + w*16 + pl;
    int pj = j0 + w*16 + pl;

    // my 8 fp32 center channels (coalesced)
    float xc8[8];
    {
        const float4* xp = (const float4*)(xt + (size_t)pix * CCH + quad * 8);
        float4 v0 = xp[0], v1 = xp[1];
        xc8[0]=v0.x; xc8[1]=v0.y; xc8[2]=v0.z; xc8[3]=v0.w;
        xc8[4]=v1.x; xc8[5]=v1.y; xc8[6]=v1.z; xc8[7]=v1.w;
    }
    // gates for my pixel (identical across quads)
    const float4* conv4 = (const float4*)(ws + WS_CONV4);
    float4 cv = conv4[pix];
    float gbv[4];
    gbv[0] = 2.f / (1.f + expf(-(cv.x * bnab[0] + bnab[4])));
    gbv[1] = 2.f / (1.f + expf(-(cv.y * bnab[1] + bnab[5])));
    gbv[2] = 2.f / (1.f + expf(-(cv.z * bnab[2] + bnab[6])));
    gbv[3] = 2.f / (1.f + expf(-(cv.w * bnab[3] + bnab[7])));

    f32x4 acc0 = {0.f,0.f,0.f,0.f}, acc1 = {0.f,0.f,0.f,0.f};
    float fi = (float)i + 2.f, fj = (float)pj + 2.f;

    #pragma unroll
    for (int n = 0; n < 16; n++) {
        float mx = 0.f, my = 0.f;
        if (n < 4)       mx = -gbv[0];
        else if (n < 8)  my =  gbv[3];
        else if (n < 12) mx =  gbv[1];
        else             my = -gbv[2];
        float px = fi + prfx[n] + mx;
        float py = fj + prfy[n] + my;
        float qlx = floorf(px), qly = floorf(py);
        int qlxi = min(max((int)qlx, 0), HWP);
        int qlyi = min(max((int)qly, 0), HWP);
        int qrxi = min(max((int)qlx + 1, 0), HWP);
        int qryi = min(max((int)qly + 1, 0), HWP);
        float pxc = fminf(fmaxf(px, 0.f), (float)HWP);
        float pyc = fminf(fmaxf(py, 0.f), (float)HWP);
        float glt = (1.f + ((float)qlxi - pxc)) * (1.f + ((float)qlyi - pyc));
        float grb = (1.f - ((float)qrxi - pxc)) * (1.f - ((float)qryi - pyc));
        // edge pad: x_pad[a] = x[clamp(a-2,0,127)]
        int ltr = min(max(qlxi - 2, 0), HH - 1), ltc = min(max(qlyi - 2, 0), WW - 1);
        int rbr = min(max(qrxi - 2, 0), HH - 1), rbc = min(max(qryi - 2, 0), WW - 1);
        // tile-local coords, layout ((r*72+cc)*5+q)*8
        int lt_off = (((ltr - i + 4)*72 + (ltc - j0 + 4))*5 + quad) * 8;
        int rb_off = (((rbr - i + 4)*72 + (rbc - j0 + 4))*5 + quad) * 8;
        uint4 lw = *(const uint4*)(tile + lt_off);
        uint4 rw = *(const uint4*)(tile + rb_off);
        float d0 = xc8[0] - (glt*bflo(lw.x) + grb*bflo(rw.x));
        float d1 = xc8[1] - (glt*bfhi(lw.x) + grb*bfhi(rw.x));
        float d2 = xc8[2] - (glt*bflo(lw.y) + grb*bflo(rw.y));
        float d3 = xc8[3] - (glt*bfhi(lw.y) + grb*bfhi(rw.y));
        float d4 = xc8[4] - (glt*bflo(lw.z) + grb*bflo(rw.z));
        float d5 = xc8[5] - (glt*bfhi(lw.z) + grb*bfhi(rw.z));
        float d6 = xc8[6] - (glt*bflo(lw.w) + grb*bflo(rw.w));
        float d7 = xc8[7] - (glt*bfhi(lw.w) + grb*bfhi(rw.w));
        uint4 bw;
        bw.x = pk2(d0, d1); bw.y = pk2(d2, d3);
        bw.z = pk2(d4, d5); bw.w = pk2(d6, d7);
        short8 bfrag = *(short8*)&bw;
        // A-frags: W rows pl and pl+16, k = n*32 + quad*8 .. +7 (L1-hot)
        short8 a0 = *(const short8*)(wkb + (size_t)pl * 512 + n*32 + quad*8);
        short8 a1 = *(const short8*)(wkb + (size_t)(pl + 16) * 512 + n*32 + quad*8);
        acc0 = __builtin_amdgcn_mfma_f32_16x16x32_bf16(a0, bfrag, acc0, 0, 0, 0);
        acc1 = __builtin_amdgcn_mfma_f32_16x16x32_bf16(a1, bfrag, acc1, 0, 0, 0);
    }
    // epilogue: col = pl (pixel), row = quad*4+reg (out channel)
    int pb = pix >> 14, pij = pix & 16383;
    float* op = out + (size_t)pb * (OUTC*HH*WW) + pij;
    #pragma unroll
    for (int r = 0; r < 4; r++) {
        int o = quad*4 + r;
        op[(size_t)o * (HH*WW)]        = acc0[r] + b_pk[o];
        op[(size_t)(o + 16) * (HH*WW)] = acc1[r] + b_pk[o + 16];
    }
}

extern "C" void kernel_launch(void* const* d_in, const int* in_sizes, int n_in,
                              void* d_out, int out_size, void* d_ws, size_t ws_size,
                              hipStream_t stream) {
    const float* x      = (const float*)d_in[0];
    const float* w_vrt  = (const float*)d_in[1];
    const float* b_vrt  = (const float*)d_in[2];
    const float* g_vrt  = (const float*)d_in[3];
    const float* be_vrt = (const float*)d_in[4];
    const float* w_hrz  = (const float*)d_in[5];
    const float* b_hrz  = (const float*)d_in[6];
    const float* g_hrz  = (const float*)d_in[7];
    const float* be_hrz = (const float*)d_in[8];
    const float* w_pk   = (const float*)d_in[9];
    const float* b_pk   = (const float*)d_in[10];
    float* ws  = (float*)d_ws;
    float* out = (float*)d_out;

    k_transpose<<<BB*HH*(WW/32), 256, 0, stream>>>(x, w_vrt, w_hrz, ws);
    k_conv<<<NPIX/64, 256, 0, stream>>>(ws, b_vrt, b_hrz);
    k_prep<<<8, 256, 0, stream>>>(w_pk, g_vrt, be_vrt, g_hrz, be_hrz, ws);
    k_main<<<NPIX/64, 256, 0, stream>>>(ws, b_pk, out);
}

// Round 12
// 169.914 us; speedup vs baseline: 1.1300x; 1.1300x over previous
//
#include <hip/hip_runtime.h>
#include <math.h>

#define BB 8
#define CCH 32
#define HH 128
#define WW 128
#define OUTC 32
#define NPIX (BB*HH*WW)          // 131072
#define HWP 131                   // padded-coord clamp limit
#define NCONVBLK 2048             // conv blocks (64 px each)

// workspace layout (float offsets) — ~18.97 MB
#define WS_XT    0                                   // fp32 x_t [b][i][j][c], 16 MB
#define WS_CONV4 (BB*HH*WW*CCH)                      // pre-BN conv, 4 f/px, 2 MB
#define WS_PART  (WS_CONV4 + BB*HH*WW*4)             // 2048*8 f per-block stats partials
#define WS_BNAB  (WS_PART + NCONVBLK*8)              // 8 f
#define WS_WKB   (WS_BNAB + 8)                       // 16384 ushort bf16 W[o][k], k=n*32+c

// k_main LDS tile: rows i0-4..i0+5 (10), cols j0-4..j0+67 (72), 5-group padding
// offset(r,cc,q) = ((r*72+cc)*5 + q)*8 ushorts; (r,cc) stride 80B -> conflict-free
#define TILE_USH (10*72*5*8)                         // 28800 ushorts = 57600 B

typedef __attribute__((ext_vector_type(8))) short short8;
typedef __attribute__((ext_vector_type(4))) float f32x4;

__device__ __forceinline__ unsigned short f2bf(float f) {
    unsigned u = __float_as_uint(f);
    unsigned r = (u + 0x7FFFu + ((u >> 16) & 1u)) >> 16;   // RTNE
    return (unsigned short)r;
}
__device__ __forceinline__ unsigned pk2(float a, float b) {
    return (unsigned)f2bf(a) | ((unsigned)f2bf(b) << 16);
}
__device__ __forceinline__ float bflo(unsigned w) { return __uint_as_float(w << 16); }
__device__ __forceinline__ float bfhi(unsigned w) { return __uint_as_float(w & 0xFFFF0000u); }

// ---------------- K1: fused transpose | NCHW conv+partials | wkb build ------
// blocks [0,4096): transpose 32x32 tile of one (b,i) row group
// blocks [4096,6144): conv for 64 px of one row, from ORIGINAL x (NCHW)
// blocks [6144,6152): bf16 weight table build
__global__ __launch_bounds__(256) void k_fused1(const float* __restrict__ x,
        const float* __restrict__ w_vrt, const float* __restrict__ b_vrt,
        const float* __restrict__ w_hrz, const float* __restrict__ b_hrz,
        const float* __restrict__ w_pk, float* __restrict__ ws) {
    __shared__ float tile[32][33];
    __shared__ float red[4][64][4];
    int blk = blockIdx.x, t = threadIdx.x;
    if (blk < 4096) {
        // ---- transpose x (B,C,H,W) -> x_t fp32 [b][i][j][c]
        int j0 = (blk & 3) << 5;
        int bi = blk >> 2;               // b*H + i
        int b = bi >> 7, i = bi & 127;
        int tx = t & 31, ty = t >> 5;
        #pragma unroll
        for (int c = ty; c < 32; c += 8)
            tile[c][tx] = x[(((size_t)b*CCH + c)*HH + i)*WW + j0 + tx];
        __syncthreads();
        float* xt = ws + WS_XT;
        #pragma unroll
        for (int jj = ty; jj < 32; jj += 8)
            xt[(((size_t)bi)*WW + j0 + jj)*CCH + tx] = tile[tx][jj];
    } else if (blk < 4096 + NCONVBLK) {
        // ---- conv: 64 px of row (b,i), cols j0c..j0c+63, from NCHW x
        int cb = blk - 4096;
        int idx0 = cb * 64;
        int b = idx0 >> 14, ij0 = idx0 & 16383, i = ij0 >> 7, j0c = ij0 & 127;
        int px = t & 63;
        int grp = __builtin_amdgcn_readfirstlane(t >> 6);  // wave-uniform ch group
        float v0 = 0.f, v1 = 0.f, h0 = 0.f, h1 = 0.f;
        for (int c8 = 0; c8 < 8; c8++) {
            int c = grp * 8 + c8;
            const float* basec = x + ((size_t)(b*CCH + c))*HH*WW;
            #pragma unroll
            for (int k = 0; k < 7; k++) {
                float wv0 = w_vrt[c*7 + k], wv1 = w_vrt[224 + c*7 + k];
                int gr = i + k - 3;
                if (gr >= 0 && gr < HH) {
                    float xv = basec[(size_t)gr*WW + j0c + px];
                    v0 += wv0 * xv; v1 += wv1 * xv;
                }
                float wh0 = w_hrz[c*7 + k], wh1 = w_hrz[224 + c*7 + k];
                int gc = j0c + px + k - 3;
                if (gc >= 0 && gc < WW) {
                    float xh = basec[(size_t)i*WW + gc];
                    h0 += wh0 * xh; h1 += wh1 * xh;
                }
            }
        }
        red[grp][px][0] = v0; red[grp][px][1] = v1;
        red[grp][px][2] = h0; red[grp][px][3] = h1;
        __syncthreads();
        if (grp == 0) {
            float fv0 = red[0][px][0]+red[1][px][0]+red[2][px][0]+red[3][px][0] + b_vrt[0];
            float fv1 = red[0][px][1]+red[1][px][1]+red[2][px][1]+red[3][px][1] + b_vrt[1];
            float fh0 = red[0][px][2]+red[1][px][2]+red[2][px][2]+red[3][px][2] + b_hrz[0];
            float fh1 = red[0][px][3]+red[1][px][3]+red[2][px][3]+red[3][px][3] + b_hrz[1];
            float4* conv4 = (float4*)(ws + WS_CONV4);
            conv4[idx0 + px] = make_float4(fv0, fv1, fh0, fh1);
            float stv[8] = {fv0, fv1, fh0, fh1, fv0*fv0, fv1*fv1, fh0*fh0, fh1*fh1};
            #pragma unroll
            for (int u = 0; u < 8; u++) {
                float s = stv[u];
                for (int off = 32; off; off >>= 1) s += __shfl_down(s, off);
                if (px == 0) ws[WS_PART + cb*8 + u] = s;   // deterministic, no atomics
            }
        }
    } else {
        // ---- wkb: bf16 W[o][k], k = n*32+c
        unsigned short* wkb = (unsigned short*)(ws + WS_WKB);
        int e = (blk - 4096 - NCONVBLK) * 2048 + t;
        for (int u = 0; u < 8; u++, e += 256) {
            int o = e >> 9, n = (e >> 5) & 15, c = e & 31;
            wkb[o*512 + n*32 + c] = f2bf(w_pk[((o*32 + c) << 4) + n]);
        }
    }
}

// ---------------- K2: reduce partials -> BN affine consts -------------------
__global__ __launch_bounds__(256) void k_prep(
        const float* __restrict__ g_vrt, const float* __restrict__ be_vrt,
        const float* __restrict__ g_hrz, const float* __restrict__ be_hrz,
        float* __restrict__ ws) {
    __shared__ float acc[32][8];
    int t = threadIdx.x;
    int s = t & 7, chunk = t >> 3;          // 32 chunks of 64 blocks
    float sum = 0.f;
    for (int m = 0; m < 64; m++)
        sum += ws[WS_PART + (size_t)(chunk*64 + m)*8 + s];
    acc[chunk][s] = sum;
    __syncthreads();
    if (t < 8) {
        float tot = 0.f;
        #pragma unroll
        for (int c = 0; c < 32; c++) tot += acc[c][t];
        acc[0][t] = tot;
    }
    __syncthreads();
    if (t < 4) {
        const float cnt = (float)NPIX;
        float mean = acc[0][t] / cnt;
        float var  = acc[0][4 + t] / cnt - mean * mean;
        float gamma = (t < 2) ? g_vrt[t] : g_hrz[t - 2];
        float beta  = (t < 2) ? be_vrt[t] : be_hrz[t - 2];
        float a = gamma * rsqrtf(var + 1e-5f);
        ws[WS_BNAB + t]     = a;
        ws[WS_BNAB + 4 + t] = beta - mean * a;
    }
}

// ---------------- K3: LDS-tiled gather + interp + MFMA, 2-row blocks --------
// 1024 blocks x 512 thr. Block = (b, rows i0..i0+1, cols j0..j0+63) = 128 px.
// Wave w: row ir = i0+(w>>2), pixels pj = j0+(w&3)*16+pl. Tile rows i0-4..i0+5.
__global__ __launch_bounds__(512) void k_main(const float* __restrict__ ws,
        const float* __restrict__ b_pk, float* __restrict__ out) {
    __shared__ unsigned short tile[TILE_USH];     // 57600 B
    const float* xt   = ws + WS_XT;
    const float* bnab = ws + WS_BNAB;
    const unsigned short* wkb = (const unsigned short*)(ws + WS_WKB);
    const float prfx[16] = {-2,-2,-2,-2, -2,-1, 0, 1,  2, 2, 2, 2, -1, 0, 1, 2};
    const float prfy[16] = {-2,-1, 0, 1,  2, 2, 2, 2, -1, 0, 1, 2, -2,-2,-2,-2};

    int t = threadIdx.x;
    int blk = blockIdx.x;                 // b(3b) | ip(6b) | jh(1b)
    int b = blk >> 7, r7 = blk & 127;
    int i0 = (r7 >> 1) * 2, j0 = (r7 & 1) * 64;

    // ---- coalesced tile load (fp32 -> bf16, edge clamp), 10 rows x 72 cols
    for (int s = t; s < 10*72*4; s += 512) {
        int q = s & 3, cc = (s >> 2) % 72, r = (s >> 2) / 72;
        int gr = min(max(i0 - 4 + r, 0), HH - 1);
        int gc = min(max(j0 - 4 + cc, 0), WW - 1);
        const float4* src = (const float4*)(xt + (((size_t)(b*HH + gr))*WW + gc)*CCH + q*8);
        float4 f0 = src[0], f1 = src[1];
        uint4 v;
        v.x = pk2(f0.x, f0.y); v.y = pk2(f0.z, f0.w);
        v.z = pk2(f1.x, f1.y); v.w = pk2(f1.z, f1.w);
        *(uint4*)(tile + ((r*72 + cc)*5 + q)*8) = v;
    }
    __syncthreads();

    int w = t >> 6, pl = t & 15, quad = (t >> 4) & 3;
    int ir = i0 + (w >> 2);
    int pj = j0 + (w & 3) * 16 + pl;
    int pix = (b << 14) + ir * WW + pj;

    // my 8 fp32 center channels (coalesced)
    float xc8[8];
    {
        const float4* xp = (const float4*)(xt + (size_t)pix * CCH + quad * 8);
        float4 v0 = xp[0], v1 = xp[1];
        xc8[0]=v0.x; xc8[1]=v0.y; xc8[2]=v0.z; xc8[3]=v0.w;
        xc8[4]=v1.x; xc8[5]=v1.y; xc8[6]=v1.z; xc8[7]=v1.w;
    }
    // gates for my pixel (identical across quads)
    const float4* conv4 = (const float4*)(ws + WS_CONV4);
    float4 cv = conv4[pix];
    float gbv[4];
    gbv[0] = 2.f / (1.f + expf(-(cv.x * bnab[0] + bnab[4])));
    gbv[1] = 2.f / (1.f + expf(-(cv.y * bnab[1] + bnab[5])));
    gbv[2] = 2.f / (1.f + expf(-(cv.z * bnab[2] + bnab[6])));
    gbv[3] = 2.f / (1.f + expf(-(cv.w * bnab[3] + bnab[7])));

    f32x4 acc0 = {0.f,0.f,0.f,0.f}, acc1 = {0.f,0.f,0.f,0.f};
    float fi = (float)ir + 2.f, fj = (float)pj + 2.f;

    #pragma unroll
    for (int n = 0; n < 16; n++) {
        float mx = 0.f, my = 0.f;
        if (n < 4)       mx = -gbv[0];
        else if (n < 8)  my =  gbv[3];
        else if (n < 12) mx =  gbv[1];
        else             my = -gbv[2];
        float px = fi + prfx[n] + mx;
        float py = fj + prfy[n] + my;
        float qlx = floorf(px), qly = floorf(py);
        int qlxi = min(max((int)qlx, 0), HWP);
        int qlyi = min(max((int)qly, 0), HWP);
        int qrxi = min(max((int)qlx + 1, 0), HWP);
        int qryi = min(max((int)qly + 1, 0), HWP);
        float pxc = fminf(fmaxf(px, 0.f), (float)HWP);
        float pyc = fminf(fmaxf(py, 0.f), (float)HWP);
        float glt = (1.f + ((float)qlxi - pxc)) * (1.f + ((float)qlyi - pyc));
        float grb = (1.f - ((float)qrxi - pxc)) * (1.f - ((float)qryi - pyc));
        // edge pad: x_pad[a] = x[clamp(a-2,0,127)]
        int ltr = min(max(qlxi - 2, 0), HH - 1), ltc = min(max(qlyi - 2, 0), WW - 1);
        int rbr = min(max(qrxi - 2, 0), HH - 1), rbc = min(max(qryi - 2, 0), WW - 1);
        // tile-local coords: r = ltr - (i0-4) in [0,9], cc = ltc - (j0-4) in [0,71]
        int lt_off = (((ltr - i0 + 4)*72 + (ltc - j0 + 4))*5 + quad) * 8;
        int rb_off = (((rbr - i0 + 4)*72 + (rbc - j0 + 4))*5 + quad) * 8;
        uint4 lw = *(const uint4*)(tile + lt_off);
        uint4 rw = *(const uint4*)(tile + rb_off);
        float d0 = xc8[0] - (glt*bflo(lw.x) + grb*bflo(rw.x));
        float d1 = xc8[1] - (glt*bfhi(lw.x) + grb*bfhi(rw.x));
        float d2 = xc8[2] - (glt*bflo(lw.y) + grb*bflo(rw.y));
        float d3 = xc8[3] - (glt*bfhi(lw.y) + grb*bfhi(rw.y));
        float d4 = xc8[4] - (glt*bflo(lw.z) + grb*bflo(rw.z));
        float d5 = xc8[5] - (glt*bfhi(lw.z) + grb*bfhi(rw.z));
        float d6 = xc8[6] - (glt*bflo(lw.w) + grb*bflo(rw.w));
        float d7 = xc8[7] - (glt*bfhi(lw.w) + grb*bfhi(rw.w));
        uint4 bw;
        bw.x = pk2(d0, d1); bw.y = pk2(d2, d3);
        bw.z = pk2(d4, d5); bw.w = pk2(d6, d7);
        short8 bfrag = *(short8*)&bw;
        // A-frags: W rows pl and pl+16, k = n*32 + quad*8 .. +7 (L1-hot)
        short8 a0 = *(const short8*)(wkb + (size_t)pl * 512 + n*32 + quad*8);
        short8 a1 = *(const short8*)(wkb + (size_t)(pl + 16) * 512 + n*32 + quad*8);
        acc0 = __builtin_amdgcn_mfma_f32_16x16x32_bf16(a0, bfrag, acc0, 0, 0, 0);
        acc1 = __builtin_amdgcn_mfma_f32_16x16x32_bf16(a1, bfrag, acc1, 0, 0, 0);
    }
    // epilogue: col = pl (pixel), row = quad*4+reg (out channel)
    int pij = ir * WW + pj;
    float* op = out + (size_t)b * (OUTC*HH*WW) + pij;
    #pragma unroll
    for (int r = 0; r < 4; r++) {
        int o = quad*4 + r;
        op[(size_t)o * (HH*WW)]        = acc0[r] + b_pk[o];
        op[(size_t)(o + 16) * (HH*WW)] = acc1[r] + b_pk[o + 16];
    }
}

extern "C" void kernel_launch(void* const* d_in, const int* in_sizes, int n_in,
                              void* d_out, int out_size, void* d_ws, size_t ws_size,
                              hipStream_t stream) {
    const float* x      = (const float*)d_in[0];
    const float* w_vrt  = (const float*)d_in[1];
    const float* b_vrt  = (const float*)d_in[2];
    const float* g_vrt  = (const float*)d_in[3];
    const float* be_vrt = (const float*)d_in[4];
    const float* w_hrz  = (const float*)d_in[5];
    const float* b_hrz  = (const float*)d_in[6];
    const float* g_hrz  = (const float*)d_in[7];
    const float* be_hrz = (const float*)d_in[8];
    const float* w_pk   = (const float*)d_in[9];
    const float* b_pk   = (const float*)d_in[10];
    float* ws  = (float*)d_ws;
    float* out = (float*)d_out;

    k_fused1<<<4096 + NCONVBLK + 8, 256, 0, stream>>>(x, w_vrt, b_vrt, w_hrz, b_hrz, w_pk, ws);
    k_prep<<<1, 256, 0, stream>>>(g_vrt, be_vrt, g_hrz, be_hrz, ws);
    k_main<<<1024, 512, 0, stream>>>(ws, b_pk, out);
}

// Round 13
// 161.704 us; speedup vs baseline: 1.1874x; 1.0508x over previous
//
#include <hip/hip_runtime.h>
#include <math.h>

#define BB 8
#define CCH 32
#define HH 128
#define WW 128
#define OUTC 32
#define NPIX (BB*HH*WW)          // 131072
#define HWP 131                   // padded-coord clamp limit
#define NCONVBLK 2048             // conv blocks (64 px each)

// workspace layout (float offsets) — ~18.97 MB
#define WS_XT    0                                   // fp32 x_t [b][i][j][c], 16 MB
#define WS_CONV4 (BB*HH*WW*CCH)                      // pre-BN conv, 4 f/px, 2 MB
#define WS_PART  (WS_CONV4 + BB*HH*WW*4)             // 2048*8 f per-block stats partials
#define WS_BNAB  (WS_PART + NCONVBLK*8)              // 8 f
#define WS_WKB   (WS_BNAB + 8)                       // 16384 ushort bf16 W[o][k], k=n*32+c

// k_main LDS tile: rows i0-4..i0+7 (12), cols j0-4..j0+35 (40), 5-group padding
// offset(r,cc,q) = ((r*40+cc)*5 + q)*8 ushorts; (r,cc) stride 80B -> conflict-light
#define TILE_USH (12*40*5*8)                         // 19200 ushorts = 38400 B

typedef __attribute__((ext_vector_type(8))) short short8;
typedef __attribute__((ext_vector_type(4))) float f32x4;

__device__ __forceinline__ unsigned short f2bf(float f) {
    unsigned u = __float_as_uint(f);
    unsigned r = (u + 0x7FFFu + ((u >> 16) & 1u)) >> 16;   // RTNE
    return (unsigned short)r;
}
__device__ __forceinline__ unsigned pk2(float a, float b) {
    return (unsigned)f2bf(a) | ((unsigned)f2bf(b) << 16);
}
__device__ __forceinline__ float bflo(unsigned w) { return __uint_as_float(w << 16); }
__device__ __forceinline__ float bfhi(unsigned w) { return __uint_as_float(w & 0xFFFF0000u); }

// ---------------- K1: fused transpose | NCHW conv+partials | wkb build ------
// blocks [0,4096): transpose 32x32 tile of one (b,i) row group
// blocks [4096,6144): conv for 64 px of one row, from ORIGINAL x (NCHW)
// blocks [6144,6152): bf16 weight table build
__global__ __launch_bounds__(256) void k_fused1(const float* __restrict__ x,
        const float* __restrict__ w_vrt, const float* __restrict__ b_vrt,
        const float* __restrict__ w_hrz, const float* __restrict__ b_hrz,
        const float* __restrict__ w_pk, float* __restrict__ ws) {
    __shared__ float tile[32][33];
    __shared__ float red[4][64][4];
    int blk = blockIdx.x, t = threadIdx.x;
    if (blk < 4096) {
        // ---- transpose x (B,C,H,W) -> x_t fp32 [b][i][j][c]
        int j0 = (blk & 3) << 5;
        int bi = blk >> 2;               // b*H + i
        int b = bi >> 7, i = bi & 127;
        int tx = t & 31, ty = t >> 5;
        #pragma unroll
        for (int c = ty; c < 32; c += 8)
            tile[c][tx] = x[(((size_t)b*CCH + c)*HH + i)*WW + j0 + tx];
        __syncthreads();
        float* xt = ws + WS_XT;
        #pragma unroll
        for (int jj = ty; jj < 32; jj += 8)
            xt[(((size_t)bi)*WW + j0 + jj)*CCH + tx] = tile[tx][jj];
    } else if (blk < 4096 + NCONVBLK) {
        // ---- conv: 64 px of row (b,i), cols j0c..j0c+63, from NCHW x
        int cb = blk - 4096;
        int idx0 = cb * 64;
        int b = idx0 >> 14, ij0 = idx0 & 16383, i = ij0 >> 7, j0c = ij0 & 127;
        int px = t & 63;
        int grp = __builtin_amdgcn_readfirstlane(t >> 6);  // wave-uniform ch group
        float v0 = 0.f, v1 = 0.f, h0 = 0.f, h1 = 0.f;
        for (int c8 = 0; c8 < 8; c8++) {
            int c = grp * 8 + c8;
            const float* basec = x + ((size_t)(b*CCH + c))*HH*WW;
            #pragma unroll
            for (int k = 0; k < 7; k++) {
                float wv0 = w_vrt[c*7 + k], wv1 = w_vrt[224 + c*7 + k];
                int gr = i + k - 3;
                if (gr >= 0 && gr < HH) {
                    float xv = basec[(size_t)gr*WW + j0c + px];
                    v0 += wv0 * xv; v1 += wv1 * xv;
                }
                float wh0 = w_hrz[c*7 + k], wh1 = w_hrz[224 + c*7 + k];
                int gc = j0c + px + k - 3;
                if (gc >= 0 && gc < WW) {
                    float xh = basec[(size_t)i*WW + gc];
                    h0 += wh0 * xh; h1 += wh1 * xh;
                }
            }
        }
        red[grp][px][0] = v0; red[grp][px][1] = v1;
        red[grp][px][2] = h0; red[grp][px][3] = h1;
        __syncthreads();
        if (grp == 0) {
            float fv0 = red[0][px][0]+red[1][px][0]+red[2][px][0]+red[3][px][0] + b_vrt[0];
            float fv1 = red[0][px][1]+red[1][px][1]+red[2][px][1]+red[3][px][1] + b_vrt[1];
            float fh0 = red[0][px][2]+red[1][px][2]+red[2][px][2]+red[3][px][2] + b_hrz[0];
            float fh1 = red[0][px][3]+red[1][px][3]+red[2][px][3]+red[3][px][3] + b_hrz[1];
            float4* conv4 = (float4*)(ws + WS_CONV4);
            conv4[idx0 + px] = make_float4(fv0, fv1, fh0, fh1);
            float stv[8] = {fv0, fv1, fh0, fh1, fv0*fv0, fv1*fv1, fh0*fh0, fh1*fh1};
            #pragma unroll
            for (int u = 0; u < 8; u++) {
                float s = stv[u];
                for (int off = 32; off; off >>= 1) s += __shfl_down(s, off);
                if (px == 0) ws[WS_PART + cb*8 + u] = s;   // deterministic, no atomics
            }
        }
    } else {
        // ---- wkb: bf16 W[o][k], k = n*32+c
        unsigned short* wkb = (unsigned short*)(ws + WS_WKB);
        int e = (blk - 4096 - NCONVBLK) * 2048 + t;
        for (int u = 0; u < 8; u++, e += 256) {
            int o = e >> 9, n = (e >> 5) & 15, c = e & 31;
            wkb[o*512 + n*32 + c] = f2bf(w_pk[((o*32 + c) << 4) + n]);
        }
    }
}

// ---------------- K2: reduce partials -> BN affine consts -------------------
__global__ __launch_bounds__(256) void k_prep(
        const float* __restrict__ g_vrt, const float* __restrict__ be_vrt,
        const float* __restrict__ g_hrz, const float* __restrict__ be_hrz,
        float* __restrict__ ws) {
    __shared__ float acc[32][8];
    int t = threadIdx.x;
    int s = t & 7, chunk = t >> 3;          // 32 chunks of 64 blocks
    float sum = 0.f;
    for (int m = 0; m < 64; m++)
        sum += ws[WS_PART + (size_t)(chunk*64 + m)*8 + s];
    acc[chunk][s] = sum;
    __syncthreads();
    if (t < 8) {
        float tot = 0.f;
        #pragma unroll
        for (int c = 0; c < 32; c++) tot += acc[c][t];
        acc[0][t] = tot;
    }
    __syncthreads();
    if (t < 4) {
        const float cnt = (float)NPIX;
        float mean = acc[0][t] / cnt;
        float var  = acc[0][4 + t] / cnt - mean * mean;
        float gamma = (t < 2) ? g_vrt[t] : g_hrz[t - 2];
        float beta  = (t < 2) ? be_vrt[t] : be_hrz[t - 2];
        float a = gamma * rsqrtf(var + 1e-5f);
        ws[WS_BNAB + t]     = a;
        ws[WS_BNAB + 4 + t] = beta - mean * a;
    }
}

// ---------------- K3: LDS-tiled gather + interp + MFMA, 4-row x 32-col ------
// 1024 blocks x 512 thr. Block = (b, rows i0..i0+3, cols j0..j0+31) = 128 px.
// Wave w (0..7): row ir = i0+(w>>1), pixels pj = j0+(w&1)*16+pl.
// Tile rows i0-4..i0+7 (12), cols j0-4..j0+35 (40): 38.4 KB -> 4 blocks/CU.
__global__ __launch_bounds__(512) void k_main(const float* __restrict__ ws,
        const float* __restrict__ b_pk, float* __restrict__ out) {
    __shared__ unsigned short tile[TILE_USH];     // 38400 B
    const float* xt   = ws + WS_XT;
    const float* bnab = ws + WS_BNAB;
    const unsigned short* wkb = (const unsigned short*)(ws + WS_WKB);
    const float prfx[16] = {-2,-2,-2,-2, -2,-1, 0, 1,  2, 2, 2, 2, -1, 0, 1, 2};
    const float prfy[16] = {-2,-1, 0, 1,  2, 2, 2, 2, -1, 0, 1, 2, -2,-2,-2,-2};

    int t = threadIdx.x;
    int blk = blockIdx.x;                 // b(3b) | ig(5b) | jh(2b)
    int b = blk >> 7;
    int i0 = ((blk >> 2) & 31) * 4;
    int j0 = (blk & 3) * 32;

    // ---- coalesced tile load (fp32 -> bf16, edge clamp), 12 rows x 40 cols
    for (int s = t; s < 12*40*4; s += 512) {
        int q = s & 3, cc = (s >> 2) % 40, r = (s >> 2) / 40;
        int gr = min(max(i0 - 4 + r, 0), HH - 1);
        int gc = min(max(j0 - 4 + cc, 0), WW - 1);
        const float4* src = (const float4*)(xt + (((size_t)(b*HH + gr))*WW + gc)*CCH + q*8);
        float4 f0 = src[0], f1 = src[1];
        uint4 v;
        v.x = pk2(f0.x, f0.y); v.y = pk2(f0.z, f0.w);
        v.z = pk2(f1.x, f1.y); v.w = pk2(f1.z, f1.w);
        *(uint4*)(tile + ((r*40 + cc)*5 + q)*8) = v;
    }
    __syncthreads();

    int w = t >> 6, pl = t & 15, quad = (t >> 4) & 3;
    int ir = i0 + (w >> 1);
    int pj = j0 + (w & 1) * 16 + pl;
    int pix = (b << 14) + ir * WW + pj;

    // my 8 fp32 center channels (coalesced)
    float xc8[8];
    {
        const float4* xp = (const float4*)(xt + (size_t)pix * CCH + quad * 8);
        float4 v0 = xp[0], v1 = xp[1];
        xc8[0]=v0.x; xc8[1]=v0.y; xc8[2]=v0.z; xc8[3]=v0.w;
        xc8[4]=v1.x; xc8[5]=v1.y; xc8[6]=v1.z; xc8[7]=v1.w;
    }
    // gates for my pixel (identical across quads)
    const float4* conv4 = (const float4*)(ws + WS_CONV4);
    float4 cv = conv4[pix];
    float gbv[4];
    gbv[0] = 2.f / (1.f + expf(-(cv.x * bnab[0] + bnab[4])));
    gbv[1] = 2.f / (1.f + expf(-(cv.y * bnab[1] + bnab[5])));
    gbv[2] = 2.f / (1.f + expf(-(cv.z * bnab[2] + bnab[6])));
    gbv[3] = 2.f / (1.f + expf(-(cv.w * bnab[3] + bnab[7])));

    f32x4 acc0 = {0.f,0.f,0.f,0.f}, acc1 = {0.f,0.f,0.f,0.f};
    float fi = (float)ir + 2.f, fj = (float)pj + 2.f;

    #pragma unroll
    for (int n = 0; n < 16; n++) {
        float mx = 0.f, my = 0.f;
        if (n < 4)       mx = -gbv[0];
        else if (n < 8)  my =  gbv[3];
        else if (n < 12) mx =  gbv[1];
        else             my = -gbv[2];
        float px = fi + prfx[n] + mx;
        float py = fj + prfy[n] + my;
        float qlx = floorf(px), qly = floorf(py);
        int qlxi = min(max((int)qlx, 0), HWP);
        int qlyi = min(max((int)qly, 0), HWP);
        int qrxi = min(max((int)qlx + 1, 0), HWP);
        int qryi = min(max((int)qly + 1, 0), HWP);
        float pxc = fminf(fmaxf(px, 0.f), (float)HWP);
        float pyc = fminf(fmaxf(py, 0.f), (float)HWP);
        float glt = (1.f + ((float)qlxi - pxc)) * (1.f + ((float)qlyi - pyc));
        float grb = (1.f - ((float)qrxi - pxc)) * (1.f - ((float)qryi - pyc));
        // edge pad: x_pad[a] = x[clamp(a-2,0,127)]
        int ltr = min(max(qlxi - 2, 0), HH - 1), ltc = min(max(qlyi - 2, 0), WW - 1);
        int rbr = min(max(qrxi - 2, 0), HH - 1), rbc = min(max(qryi - 2, 0), WW - 1);
        // tile-local coords: r = ltr-(i0-4) in [0,11], cc = ltc-(j0-4) in [0,39]
        int lt_off = (((ltr - i0 + 4)*40 + (ltc - j0 + 4))*5 + quad) * 8;
        int rb_off = (((rbr - i0 + 4)*40 + (rbc - j0 + 4))*5 + quad) * 8;
        uint4 lw = *(const uint4*)(tile + lt_off);
        uint4 rw = *(const uint4*)(tile + rb_off);
        float d0 = xc8[0] - (glt*bflo(lw.x) + grb*bflo(rw.x));
        float d1 = xc8[1] - (glt*bfhi(lw.x) + grb*bfhi(rw.x));
        float d2 = xc8[2] - (glt*bflo(lw.y) + grb*bflo(rw.y));
        float d3 = xc8[3] - (glt*bfhi(lw.y) + grb*bfhi(rw.y));
        float d4 = xc8[4] - (glt*bflo(lw.z) + grb*bflo(rw.z));
        float d5 = xc8[5] - (glt*bfhi(lw.z) + grb*bfhi(rw.z));
        float d6 = xc8[6] - (glt*bflo(lw.w) + grb*bflo(rw.w));
        float d7 = xc8[7] - (glt*bfhi(lw.w) + grb*bfhi(rw.w));
        uint4 bw;
        bw.x = pk2(d0, d1); bw.y = pk2(d2, d3);
        bw.z = pk2(d4, d5); bw.w = pk2(d6, d7);
        short8 bfrag = *(short8*)&bw;
        // A-frags: W rows pl and pl+16, k = n*32 + quad*8 .. +7 (L1-hot)
        short8 a0 = *(const short8*)(wkb + (size_t)pl * 512 + n*32 + quad*8);
        short8 a1 = *(const short8*)(wkb + (size_t)(pl + 16) * 512 + n*32 + quad*8);
        acc0 = __builtin_amdgcn_mfma_f32_16x16x32_bf16(a0, bfrag, acc0, 0, 0, 0);
        acc1 = __builtin_amdgcn_mfma_f32_16x16x32_bf16(a1, bfrag, acc1, 0, 0, 0);
    }
    // epilogue: col = pl (pixel), row = quad*4+reg (out channel)
    int pij = ir * WW + pj;
    float* op = out + (size_t)b * (OUTC*HH*WW) + pij;
    #pragma unroll
    for (int r = 0; r < 4; r++) {
        int o = quad*4 + r;
        op[(size_t)o * (HH*WW)]        = acc0[r] + b_pk[o];
        op[(size_t)(o + 16) * (HH*WW)] = acc1[r] + b_pk[o + 16];
    }
}

extern "C" void kernel_launch(void* const* d_in, const int* in_sizes, int n_in,
                              void* d_out, int out_size, void* d_ws, size_t ws_size,
                              hipStream_t stream) {
    const float* x      = (const float*)d_in[0];
    const float* w_vrt  = (const float*)d_in[1];
    const float* b_vrt  = (const float*)d_in[2];
    const float* g_vrt  = (const float*)d_in[3];
    const float* be_vrt = (const float*)d_in[4];
    const float* w_hrz  = (const float*)d_in[5];
    const float* b_hrz  = (const float*)d_in[6];
    const float* g_hrz  = (const float*)d_in[7];
    const float* be_hrz = (const float*)d_in[8];
    const float* w_pk   = (const float*)d_in[9];
    const float* b_pk   = (const float*)d_in[10];
    float* ws  = (float*)d_ws;
    float* out = (float*)d_out;

    k_fused1<<<4096 + NCONVBLK + 8, 256, 0, stream>>>(x, w_vrt, b_vrt, w_hrz, b_hrz, w_pk, ws);
    k_prep<<<1, 256, 0, stream>>>(g_vrt, be_vrt, g_hrz, be_hrz, ws);
    k_main<<<1024, 512, 0, stream>>>(ws, b_pk, out);
}

// Round 14
// 158.169 us; speedup vs baseline: 1.2140x; 1.0223x over previous
//
#include <hip/hip_runtime.h>
#include <math.h>

#define BB 8
#define CCH 32
#define HH 128
#define WW 128
#define OUTC 32
#define NPIX (BB*HH*WW)          // 131072
#define HWP 131                   // padded-coord clamp limit
#define NCONVBLK 2048             // conv blocks (64 px each)

// workspace layout (float offsets) — ~18.97 MB
#define WS_XT    0                                   // fp32 x_t [b][i][j][c], 16 MB
#define WS_CONV4 (BB*HH*WW*CCH)                      // pre-BN conv, 4 f/px, 2 MB
#define WS_PART  (WS_CONV4 + BB*HH*WW*4)             // 2048*8 f per-block stats partials
#define WS_BNAB  (WS_PART + NCONVBLK*8)              // 8 f
#define WS_WKB   (WS_BNAB + 8)                       // 16384 ushort bf16 W[o][k], k=n*32+c

// k_main LDS tile: rows i0-4..i0+7 (12), cols j0-4..j0+35 (40), 5-group padding
// offset(r,cc,q) = ((r*40+cc)*5 + q)*8 ushorts; (r,cc) stride 80B
#define TILE_USH (12*40*5*8)                         // 19200 ushorts = 38400 B

typedef __attribute__((ext_vector_type(8))) short short8;
typedef __attribute__((ext_vector_type(4))) float f32x4;

__device__ __forceinline__ unsigned short f2bf(float f) {
    unsigned u = __float_as_uint(f);
    unsigned r = (u + 0x7FFFu + ((u >> 16) & 1u)) >> 16;   // RTNE
    return (unsigned short)r;
}
__device__ __forceinline__ unsigned pk2(float a, float b) {
    return (unsigned)f2bf(a) | ((unsigned)f2bf(b) << 16);
}
__device__ __forceinline__ float bflo(unsigned w) { return __uint_as_float(w << 16); }
__device__ __forceinline__ float bfhi(unsigned w) { return __uint_as_float(w & 0xFFFF0000u); }

// ---------------- K1: fused transpose | NCHW conv+partials | wkb build ------
__global__ __launch_bounds__(256) void k_fused1(const float* __restrict__ x,
        const float* __restrict__ w_vrt, const float* __restrict__ b_vrt,
        const float* __restrict__ w_hrz, const float* __restrict__ b_hrz,
        const float* __restrict__ w_pk, float* __restrict__ ws) {
    __shared__ float tile[32][33];
    __shared__ float red[4][64][4];
    int blk = blockIdx.x, t = threadIdx.x;
    if (blk < 4096) {
        // ---- transpose x (B,C,H,W) -> x_t fp32 [b][i][j][c]
        int j0 = (blk & 3) << 5;
        int bi = blk >> 2;               // b*H + i
        int b = bi >> 7, i = bi & 127;
        int tx = t & 31, ty = t >> 5;
        #pragma unroll
        for (int c = ty; c < 32; c += 8)
            tile[c][tx] = x[(((size_t)b*CCH + c)*HH + i)*WW + j0 + tx];
        __syncthreads();
        float* xt = ws + WS_XT;
        #pragma unroll
        for (int jj = ty; jj < 32; jj += 8)
            xt[(((size_t)bi)*WW + j0 + jj)*CCH + tx] = tile[tx][jj];
    } else if (blk < 4096 + NCONVBLK) {
        // ---- conv: 64 px of row (b,i), cols j0c..j0c+63, from NCHW x
        int cb = blk - 4096;
        int idx0 = cb * 64;
        int b = idx0 >> 14, ij0 = idx0 & 16383, i = ij0 >> 7, j0c = ij0 & 127;
        int px = t & 63;
        int grp = __builtin_amdgcn_readfirstlane(t >> 6);  // wave-uniform ch group
        float v0 = 0.f, v1 = 0.f, h0 = 0.f, h1 = 0.f;
        for (int c8 = 0; c8 < 8; c8++) {
            int c = grp * 8 + c8;
            const float* basec = x + ((size_t)(b*CCH + c))*HH*WW;
            #pragma unroll
            for (int k = 0; k < 7; k++) {
                float wv0 = w_vrt[c*7 + k], wv1 = w_vrt[224 + c*7 + k];
                int gr = i + k - 3;
                if (gr >= 0 && gr < HH) {
                    float xv = basec[(size_t)gr*WW + j0c + px];
                    v0 += wv0 * xv; v1 += wv1 * xv;
                }
                float wh0 = w_hrz[c*7 + k], wh1 = w_hrz[224 + c*7 + k];
                int gc = j0c + px + k - 3;
                if (gc >= 0 && gc < WW) {
                    float xh = basec[(size_t)i*WW + gc];
                    h0 += wh0 * xh; h1 += wh1 * xh;
                }
            }
        }
        red[grp][px][0] = v0; red[grp][px][1] = v1;
        red[grp][px][2] = h0; red[grp][px][3] = h1;
        __syncthreads();
        if (grp == 0) {
            float fv0 = red[0][px][0]+red[1][px][0]+red[2][px][0]+red[3][px][0] + b_vrt[0];
            float fv1 = red[0][px][1]+red[1][px][1]+red[2][px][1]+red[3][px][1] + b_vrt[1];
            float fh0 = red[0][px][2]+red[1][px][2]+red[2][px][2]+red[3][px][2] + b_hrz[0];
            float fh1 = red[0][px][3]+red[1][px][3]+red[2][px][3]+red[3][px][3] + b_hrz[1];
            float4* conv4 = (float4*)(ws + WS_CONV4);
            conv4[idx0 + px] = make_float4(fv0, fv1, fh0, fh1);
            float stv[8] = {fv0, fv1, fh0, fh1, fv0*fv0, fv1*fv1, fh0*fh0, fh1*fh1};
            #pragma unroll
            for (int u = 0; u < 8; u++) {
                float s = stv[u];
                for (int off = 32; off; off >>= 1) s += __shfl_down(s, off);
                if (px == 0) ws[WS_PART + cb*8 + u] = s;   // deterministic, no atomics
            }
        }
    } else {
        // ---- wkb: bf16 W[o][k], k = n*32+c
        unsigned short* wkb = (unsigned short*)(ws + WS_WKB);
        int e = (blk - 4096 - NCONVBLK) * 2048 + t;
        for (int u = 0; u < 8; u++, e += 256) {
            int o = e >> 9, n = (e >> 5) & 15, c = e & 31;
            wkb[o*512 + n*32 + c] = f2bf(w_pk[((o*32 + c) << 4) + n]);
        }
    }
}

// ---------------- K2: reduce partials -> BN affine consts -------------------
__global__ __launch_bounds__(256) void k_prep(
        const float* __restrict__ g_vrt, const float* __restrict__ be_vrt,
        const float* __restrict__ g_hrz, const float* __restrict__ be_hrz,
        float* __restrict__ ws) {
    __shared__ float acc[32][8];
    int t = threadIdx.x;
    int s = t & 7, chunk = t >> 3;          // 32 chunks of 64 blocks
    float sum = 0.f;
    for (int m = 0; m < 64; m++)
        sum += ws[WS_PART + (size_t)(chunk*64 + m)*8 + s];
    acc[chunk][s] = sum;
    __syncthreads();
    if (t < 8) {
        float tot = 0.f;
        #pragma unroll
        for (int c = 0; c < 32; c++) tot += acc[c][t];
        acc[0][t] = tot;
    }
    __syncthreads();
    if (t < 4) {
        const float cnt = (float)NPIX;
        float mean = acc[0][t] / cnt;
        float var  = acc[0][4 + t] / cnt - mean * mean;
        float gamma = (t < 2) ? g_vrt[t] : g_hrz[t - 2];
        float beta  = (t < 2) ? be_vrt[t] : be_hrz[t - 2];
        float a = gamma * rsqrtf(var + 1e-5f);
        ws[WS_BNAB + t]     = a;
        ws[WS_BNAB + 4 + t] = beta - mean * a;
    }
}

// per-(pixel,n) sampling: returns bf16 B-fragment (8 ch = quad slice)
__device__ __forceinline__ short8 sample_frag(const unsigned short* tile,
        const float* xc8, const float* gbv, float fi, float fj, int n,
        float prx, float pry, int i0, int j0, int quad) {
    float mx = 0.f, my = 0.f;
    if (n < 4)       mx = -gbv[0];
    else if (n < 8)  my =  gbv[3];
    else if (n < 12) mx =  gbv[1];
    else             my = -gbv[2];
    float px = fi + prx + mx;
    float py = fj + pry + my;
    float qlx = floorf(px), qly = floorf(py);
    int qlxi = min(max((int)qlx, 0), HWP);
    int qlyi = min(max((int)qly, 0), HWP);
    int qrxi = min(max((int)qlx + 1, 0), HWP);
    int qryi = min(max((int)qly + 1, 0), HWP);
    float pxc = fminf(fmaxf(px, 0.f), (float)HWP);
    float pyc = fminf(fmaxf(py, 0.f), (float)HWP);
    float glt = (1.f + ((float)qlxi - pxc)) * (1.f + ((float)qlyi - pyc));
    float grb = (1.f - ((float)qrxi - pxc)) * (1.f - ((float)qryi - pyc));
    // edge pad: x_pad[a] = x[clamp(a-2,0,127)]
    int ltr = min(max(qlxi - 2, 0), HH - 1), ltc = min(max(qlyi - 2, 0), WW - 1);
    int rbr = min(max(qrxi - 2, 0), HH - 1), rbc = min(max(qryi - 2, 0), WW - 1);
    int lt_off = (((ltr - i0 + 4)*40 + (ltc - j0 + 4))*5 + quad) * 8;
    int rb_off = (((rbr - i0 + 4)*40 + (rbc - j0 + 4))*5 + quad) * 8;
    uint4 lw = *(const uint4*)(tile + lt_off);
    uint4 rw = *(const uint4*)(tile + rb_off);
    float d0 = xc8[0] - (glt*bflo(lw.x) + grb*bflo(rw.x));
    float d1 = xc8[1] - (glt*bfhi(lw.x) + grb*bfhi(rw.x));
    float d2 = xc8[2] - (glt*bflo(lw.y) + grb*bflo(rw.y));
    float d3 = xc8[3] - (glt*bfhi(lw.y) + grb*bfhi(rw.y));
    float d4 = xc8[4] - (glt*bflo(lw.z) + grb*bflo(rw.z));
    float d5 = xc8[5] - (glt*bfhi(lw.z) + grb*bfhi(rw.z));
    float d6 = xc8[6] - (glt*bflo(lw.w) + grb*bflo(rw.w));
    float d7 = xc8[7] - (glt*bfhi(lw.w) + grb*bfhi(rw.w));
    uint4 bw;
    bw.x = pk2(d0, d1); bw.y = pk2(d2, d3);
    bw.z = pk2(d4, d5); bw.w = pk2(d6, d7);
    return *(short8*)&bw;
}

// ---------------- K3: MFMA, 2 pixel-tiles per wave, weight prefetch ---------
// 1024 blocks x 256 thr. Block = (b, rows i0..i0+3, cols j0..j0+31) = 128 px.
// Wave w (0..3): row ir = i0+w; tile A = cols j0+pl, tile B = cols j0+16+pl.
// A-frags (weights) shared across both tiles; explicit next-n prefetch.
__global__ __launch_bounds__(256, 4) void k_main(const float* __restrict__ ws,
        const float* __restrict__ b_pk, float* __restrict__ out) {
    __shared__ unsigned short tile[TILE_USH];     // 38400 B
    const float* xt   = ws + WS_XT;
    const float* bnab = ws + WS_BNAB;
    const unsigned short* wkb = (const unsigned short*)(ws + WS_WKB);
    const float prfx[16] = {-2,-2,-2,-2, -2,-1, 0, 1,  2, 2, 2, 2, -1, 0, 1, 2};
    const float prfy[16] = {-2,-1, 0, 1,  2, 2, 2, 2, -1, 0, 1, 2, -2,-2,-2,-2};

    int t = threadIdx.x;
    int blk = blockIdx.x;                 // b(3b) | ig(5b) | jh(2b)
    int b = blk >> 7;
    int i0 = ((blk >> 2) & 31) * 4;
    int j0 = (blk & 3) * 32;

    // ---- coalesced tile load (fp32 -> bf16, edge clamp), 12 rows x 40 cols
    for (int s = t; s < 12*40*4; s += 256) {
        int q = s & 3, cc = (s >> 2) % 40, r = (s >> 2) / 40;
        int gr = min(max(i0 - 4 + r, 0), HH - 1);
        int gc = min(max(j0 - 4 + cc, 0), WW - 1);
        const float4* src = (const float4*)(xt + (((size_t)(b*HH + gr))*WW + gc)*CCH + q*8);
        float4 f0 = src[0], f1 = src[1];
        uint4 v;
        v.x = pk2(f0.x, f0.y); v.y = pk2(f0.z, f0.w);
        v.z = pk2(f1.x, f1.y); v.w = pk2(f1.z, f1.w);
        *(uint4*)(tile + ((r*40 + cc)*5 + q)*8) = v;
    }
    __syncthreads();

    int w = t >> 6, pl = t & 15, quad = (t >> 4) & 3;
    int ir = i0 + w;
    int pjA = j0 + pl, pjB = j0 + 16 + pl;
    int pixA = (b << 14) + ir * WW + pjA;
    int pixB = pixA + 16;

    // fp32 center channels for both pixels (coalesced)
    float xcA[8], xcB[8];
    {
        const float4* xpA = (const float4*)(xt + (size_t)pixA * CCH + quad * 8);
        float4 v0 = xpA[0], v1 = xpA[1];
        xcA[0]=v0.x; xcA[1]=v0.y; xcA[2]=v0.z; xcA[3]=v0.w;
        xcA[4]=v1.x; xcA[5]=v1.y; xcA[6]=v1.z; xcA[7]=v1.w;
        const float4* xpB = (const float4*)(xt + (size_t)pixB * CCH + quad * 8);
        float4 u0 = xpB[0], u1 = xpB[1];
        xcB[0]=u0.x; xcB[1]=u0.y; xcB[2]=u0.z; xcB[3]=u0.w;
        xcB[4]=u1.x; xcB[5]=u1.y; xcB[6]=u1.z; xcB[7]=u1.w;
    }
    // gates for both pixels
    const float4* conv4 = (const float4*)(ws + WS_CONV4);
    float4 cvA = conv4[pixA], cvB = conv4[pixB];
    float gbvA[4], gbvB[4];
    gbvA[0] = 2.f / (1.f + expf(-(cvA.x * bnab[0] + bnab[4])));
    gbvA[1] = 2.f / (1.f + expf(-(cvA.y * bnab[1] + bnab[5])));
    gbvA[2] = 2.f / (1.f + expf(-(cvA.z * bnab[2] + bnab[6])));
    gbvA[3] = 2.f / (1.f + expf(-(cvA.w * bnab[3] + bnab[7])));
    gbvB[0] = 2.f / (1.f + expf(-(cvB.x * bnab[0] + bnab[4])));
    gbvB[1] = 2.f / (1.f + expf(-(cvB.y * bnab[1] + bnab[5])));
    gbvB[2] = 2.f / (1.f + expf(-(cvB.z * bnab[2] + bnab[6])));
    gbvB[3] = 2.f / (1.f + expf(-(cvB.w * bnab[3] + bnab[7])));

    f32x4 accA0 = {0.f,0.f,0.f,0.f}, accA1 = {0.f,0.f,0.f,0.f};
    f32x4 accB0 = {0.f,0.f,0.f,0.f}, accB1 = {0.f,0.f,0.f,0.f};
    float fi = (float)ir + 2.f;
    float fjA = (float)pjA + 2.f, fjB = (float)pjB + 2.f;

    // weight prefetch pipeline (A-frags shared by both pixel tiles)
    short8 a0 = *(const short8*)(wkb + (size_t)pl * 512 + quad*8);
    short8 a1 = *(const short8*)(wkb + (size_t)(pl + 16) * 512 + quad*8);

    #pragma unroll
    for (int n = 0; n < 16; n++) {
        short8 na0 = a0, na1 = a1;
        if (n < 15) {
            na0 = *(const short8*)(wkb + (size_t)pl * 512 + (n+1)*32 + quad*8);
            na1 = *(const short8*)(wkb + (size_t)(pl + 16) * 512 + (n+1)*32 + quad*8);
        }
        short8 bfA = sample_frag(tile, xcA, gbvA, fi, fjA, n, prfx[n], prfy[n], i0, j0, quad);
        short8 bfB = sample_frag(tile, xcB, gbvB, fi, fjB, n, prfx[n], prfy[n], i0, j0, quad);
        accA0 = __builtin_amdgcn_mfma_f32_16x16x32_bf16(a0, bfA, accA0, 0, 0, 0);
        accA1 = __builtin_amdgcn_mfma_f32_16x16x32_bf16(a1, bfA, accA1, 0, 0, 0);
        accB0 = __builtin_amdgcn_mfma_f32_16x16x32_bf16(a0, bfB, accB0, 0, 0, 0);
        accB1 = __builtin_amdgcn_mfma_f32_16x16x32_bf16(a1, bfB, accB1, 0, 0, 0);
        a0 = na0; a1 = na1;
    }
    // epilogue: col = pl (pixel), row = quad*4+reg (out channel)
    float* opA = out + (size_t)b * (OUTC*HH*WW) + ir * WW + pjA;
    float* opB = opA + 16;
    #pragma unroll
    for (int r = 0; r < 4; r++) {
        int o = quad*4 + r;
        float bo = b_pk[o], bo16 = b_pk[o + 16];
        opA[(size_t)o * (HH*WW)]        = accA0[r] + bo;
        opA[(size_t)(o + 16) * (HH*WW)] = accA1[r] + bo16;
        opB[(size_t)o * (HH*WW)]        = accB0[r] + bo;
        opB[(size_t)(o + 16) * (HH*WW)] = accB1[r] + bo16;
    }
}

extern "C" void kernel_launch(void* const* d_in, const int* in_sizes, int n_in,
                              void* d_out, int out_size, void* d_ws, size_t ws_size,
                              hipStream_t stream) {
    const float* x      = (const float*)d_in[0];
    const float* w_vrt  = (const float*)d_in[1];
    const float* b_vrt  = (const float*)d_in[2];
    const float* g_vrt  = (const float*)d_in[3];
    const float* be_vrt = (const float*)d_in[4];
    const float* w_hrz  = (const float*)d_in[5];
    const float* b_hrz  = (const float*)d_in[6];
    const float* g_hrz  = (const float*)d_in[7];
    const float* be_hrz = (const float*)d_in[8];
    const float* w_pk   = (const float*)d_in[9];
    const float* b_pk   = (const float*)d_in[10];
    float* ws  = (float*)d_ws;
    float* out = (float*)d_out;

    k_fused1<<<4096 + NCONVBLK + 8, 256, 0, stream>>>(x, w_vrt, b_vrt, w_hrz, b_hrz, w_pk, ws);
    k_prep<<<1, 256, 0, stream>>>(g_vrt, be_vrt, g_hrz, be_hrz, ws);
    k_main<<<1024, 256, 0, stream>>>(ws, b_pk, out);
}